// Round 7
// baseline (98.975 us; speedup 1.0000x reference)
//
#include <hip/hip_runtime.h>

// Conv3D implicit GEMM, round 7: tabr LDS table (no per-chunk divides),
// slim 45.8KB LDS -> 3 blocks/CU (24 waves), vectorized+fused prep.
// x (8,3,16,112,112) f32, w (64,3,5,7,7), bias (64,) -> out (8,64,16,56,56) f32

typedef __attribute__((ext_vector_type(8))) short short8;
typedef __attribute__((ext_vector_type(4))) float f32x4;

#define CI 3
#define DI 16
#define HI 112
#define WI 112
#define CO 64
#define DO_ 16
#define HO 56
#define WO 56
#define HW_IN 12544
#define DHWO 50176

#define NROW 105
#define NCH 27

// xpad: bf16 [8][3][20 dpad][119 hpad][144 slots]; slot s = win s-3
#define XP_ROW 144
#define XP_H   119
#define XP_D   20
#define XPAD_BYTES  (8*3*XP_D*XP_H*XP_ROW*2)   // 16,434,432
#define WBUF_OFF    XPAD_BYTES
#define WS_NEED     (WBUF_OFF + NCH*4*64*16 + 4096)

#define SEG_SH 1296         // exact 9 rows * 144 shorts (2592 B)
#define SEG_DW 648

__device__ __forceinline__ unsigned short f2bf(float f) {
    unsigned u = __float_as_uint(f);
    return (unsigned short)((u + 0x7FFFu + ((u >> 16) & 1u)) >> 16);
}
__device__ __forceinline__ unsigned pk_bf16(float a, float b) {
    unsigned r;
    asm("v_cvt_pk_bf16_f32 %0, %1, %2" : "=v"(r) : "v"(a), "v"(b));
    return r;
}

// ---------- fused prep: xpad (blocks 0..4016) + weights (4017..4043) ----------
#define XP_THREADS (8*3*XP_D*XP_H*18)   // 1,028,160 (each = 8 shorts)
#define XP_BLOCKS  4017

__global__ void prep_all(const float* __restrict__ x, const float* __restrict__ wgt,
                         unsigned* __restrict__ xp, short8* __restrict__ wbuf) {
    if (blockIdx.x < XP_BLOCKS) {
        const int g = blockIdx.x * 256 + threadIdx.x;
        if (g >= XP_THREADS) return;
        const int s8 = g % 18;
        int r = g / 18;
        const int hp = r % XP_H; r /= XP_H;
        const int dp = r % XP_D; r /= XP_D;
        const int c  = r % 3;
        const int n  = r / 3;
        const int din = dp - 2, hin = hp - 3;
        const bool rowok = ((unsigned)din < (unsigned)DI) && ((unsigned)hin < (unsigned)HI);
        float v[8];
        const int w0 = 8 * s8 - 3;
        if (rowok && s8 >= 1 && s8 <= 13) {
            const float* xr = x + ((n * CI + c) * DI + din) * HW_IN + hin * WI + w0;
            #pragma unroll
            for (int j = 0; j < 8; ++j) v[j] = xr[j];
        } else if (rowok && (s8 == 0 || s8 == 14)) {
            const float* xr = x + ((n * CI + c) * DI + din) * HW_IN + hin * WI;
            #pragma unroll
            for (int j = 0; j < 8; ++j) {
                const int w = w0 + j;
                v[j] = ((unsigned)w < (unsigned)WI) ? xr[w] : 0.0f;
            }
        } else {
            #pragma unroll
            for (int j = 0; j < 8; ++j) v[j] = 0.0f;
        }
        uint4 o;
        o.x = pk_bf16(v[0], v[1]); o.y = pk_bf16(v[2], v[3]);
        o.z = pk_bf16(v[4], v[5]); o.w = pk_bf16(v[6], v[7]);
        *reinterpret_cast<uint4*>(xp + 4 * (size_t)g) = o;
    } else {
        const int t = (blockIdx.x - XP_BLOCKS) * 256 + threadIdx.x;  // 0..6911
        const int lane = t & 63;
        const int cf   = t >> 6;           // ch*4 + a
        const int l15  = lane & 15;
        const int kgrp = lane >> 4;
        const int co   = (cf & 3) * 16 + l15;
        const int rr   = (cf >> 2) * 4 + kgrp;
        const int rc   = (rr < NROW) ? rr : (NROW - 1);
        const int c    = rc / 35;
        const int kd   = (rc / 7) % 5;
        const int kh   = rc % 7;
        const float* wsrc = wgt + (((co * CI + c) * 5 + kd) * 7 + kh) * 7;
        short8 v;
        #pragma unroll
        for (int j = 0; j < 8; ++j) {
            float w = (rr < NROW && j < 7) ? wsrc[j] : 0.0f;
            v[j] = (short)f2bf(w);
        }
        wbuf[(size_t)cf * 64 + lane] = v;
    }
}

#define MFMA(A, B, C) __builtin_amdgcn_mfma_f32_16x16x32_bf16(A, B, C, 0, 0, 0)

__launch_bounds__(512, 4)
__global__ void conv3d_v7(const unsigned short* __restrict__ xpad,
                          const short8* __restrict__ wbuf,
                          const float* __restrict__ bias,
                          float* __restrict__ out) {
    __shared__ __align__(16) unsigned short xl[18 * SEG_SH];   // 46656 B
    __shared__ unsigned short tabd[112];                        // chunk-row -> dword idx

    const int tid = threadIdx.x;
    int b = blockIdx.x;
    const int ht  = b % 28;  b /= 28;
    const int ddp = b & 7;
    const int n   = b >> 3;
    const int ho0 = ht * 2;
    const int dd0 = ddp * 2;

    const int lane = tid & 63;
    const int wid  = tid >> 6;

    if (tid < 112) {
        const int rc = (tid < NROW) ? tid : (NROW - 1);
        const int c  = rc / 35;
        const int kd = (rc / 7) % 5;
        const int kh = rc % 7;
        tabd[tid] = (unsigned short)((c * 6 + kd) * SEG_DW + kh * (XP_ROW / 2));
    }

    // ---- async stage: 18 (c,p) segments of 2592B each ----
    {
        const size_t nb = (size_t)(n * CI) * XP_D;
        for (int s = wid; s < 18; s += 8) {
            const int c = s / 6;
            const int p = s - c * 6;
            const char* gsrc = (const char*)(xpad +
                ((nb + (size_t)c * XP_D + (dd0 + p)) * XP_H + 2 * ho0) * XP_ROW)
                + lane * 16;
            char* ldst = (char*)&xl[s * SEG_SH];
            __builtin_amdgcn_global_load_lds(
                (const __attribute__((address_space(1))) void*)(gsrc),
                (__attribute__((address_space(3))) void*)(ldst), 16, 0, 0);
            __builtin_amdgcn_global_load_lds(
                (const __attribute__((address_space(1))) void*)(gsrc + 1024),
                (__attribute__((address_space(3))) void*)(ldst + 1024), 16, 0, 0);
            if (lane < 34)
                __builtin_amdgcn_global_load_lds(
                    (const __attribute__((address_space(1))) void*)(gsrc + 2048),
                    (__attribute__((address_space(3))) void*)(ldst + 2048), 16, 0, 0);
        }
    }
    __syncthreads();

    // ---- wave roles: ddl x hoL x woH; wave = 64co x 32wo (28 real) ----
    const int ddl  = wid & 1;
    const int hoL  = (wid >> 1) & 1;
    const int woH  = wid >> 2;
    const int l15  = lane & 15;
    const int kgrp = lane >> 4;
    const int tbase = ddl * SEG_DW + hoL * XP_ROW + woH * 28 + l15;  // dwords

    f32x4 acc[4][2];
    #pragma unroll
    for (int a = 0; a < 4; ++a) {
        f32x4 bv;
        #pragma unroll
        for (int r = 0; r < 4; ++r) bv[r] = bias[a * 16 + kgrp * 4 + r];
        acc[a][0] = bv; acc[a][1] = bv;
    }

    const short8* wbp = wbuf + lane;
    const unsigned* xlu = reinterpret_cast<const unsigned*>(xl);

    short8 Aa[4], Ab[4];
    union BxU { unsigned u[4]; short8 s; };
    BxU pa0, pa1, pb0, pb1;

    // prologue: chunk 0 -> buffers a
    #pragma unroll
    for (int a = 0; a < 4; ++a) Aa[a] = wbp[a * 64];
    {
        const unsigned* xp = xlu + (int)tabd[kgrp] + tbase;
        #pragma unroll
        for (int j = 0; j < 4; ++j) { pa0.u[j] = xp[j]; pa1.u[j] = xp[16 + j]; }
    }

    for (int ch = 0; ch < NCH - 1; ch += 2) {
        #pragma unroll
        for (int a = 0; a < 4; ++a) Ab[a] = wbp[((ch + 1) * 4 + a) * 64];
        {
            const unsigned* xp = xlu + (int)tabd[(ch + 1) * 4 + kgrp] + tbase;
            #pragma unroll
            for (int j = 0; j < 4; ++j) { pb0.u[j] = xp[j]; pb1.u[j] = xp[16 + j]; }
        }
        #pragma unroll
        for (int a = 0; a < 4; ++a) {
            acc[a][0] = MFMA(Aa[a], pa0.s, acc[a][0]);
            acc[a][1] = MFMA(Aa[a], pa1.s, acc[a][1]);
        }
        #pragma unroll
        for (int a = 0; a < 4; ++a) Aa[a] = wbp[((ch + 2) * 4 + a) * 64];
        {
            const unsigned* xp = xlu + (int)tabd[(ch + 2) * 4 + kgrp] + tbase;
            #pragma unroll
            for (int j = 0; j < 4; ++j) { pa0.u[j] = xp[j]; pa1.u[j] = xp[16 + j]; }
        }
        #pragma unroll
        for (int a = 0; a < 4; ++a) {
            acc[a][0] = MFMA(Ab[a], pb0.s, acc[a][0]);
            acc[a][1] = MFMA(Ab[a], pb1.s, acc[a][1]);
        }
    }
    #pragma unroll
    for (int a = 0; a < 4; ++a) {
        acc[a][0] = MFMA(Aa[a], pa0.s, acc[a][0]);
        acc[a][1] = MFMA(Aa[a], pa1.s, acc[a][1]);
    }

    // ---- store (mask dead cols: f==1 && l15>=12) ----
    const int dd = dd0 + ddl;
    const int ho = ho0 + hoL;
    const size_t obase = ((((size_t)n * CO) * DO_ + dd) * HO + ho) * WO;
    #pragma unroll
    for (int f = 0; f < 2; ++f) {
        const int wo = woH * 28 + f * 16 + l15;
        if (f == 0 || l15 < 12) {
            float* op = out + obase + wo;
            #pragma unroll
            for (int a = 0; a < 4; ++a) {
                const int co = a * 16 + kgrp * 4;
                #pragma unroll
                for (int r = 0; r < 4; ++r)
                    op[(size_t)(co + r) * DHWO] = acc[a][f][r];
            }
        }
    }
}

// =================== fallback (round-5 kernel) ===================
#define FB_LR 13
#define FB_LROWS 234
#define FB_LWS 144
#define FB_XLSZ (FB_LROWS*FB_LWS)

__global__ void prep_weights_fb(const float* __restrict__ wgt, short8* __restrict__ wbuf) {
    const int t    = blockIdx.x * 64 + threadIdx.x;
    const int lane = t & 63;
    const int cf   = t >> 6;
    const int l15  = lane & 15;
    const int kgrp = lane >> 4;
    const int co   = (cf & 3) * 16 + l15;
    const int rr   = (cf >> 2) * 4 + kgrp;
    const int rc   = (rr < NROW) ? rr : (NROW - 1);
    const int c    = rc / 35;
    const int kd   = (rc / 7) % 5;
    const int kh   = rc % 7;
    const float* wsrc = wgt + (((co * CI + c) * 5 + kd) * 7 + kh) * 7;
    short8 v;
    #pragma unroll
    for (int j = 0; j < 8; ++j) {
        float w = (rr < NROW && j < 7) ? wsrc[j] : 0.0f;
        v[j] = (short)f2bf(w);
    }
    wbuf[(size_t)cf * 64 + lane] = v;
}

__launch_bounds__(512, 2)
__global__ void conv3d_mfma4(const float* __restrict__ x,
                             const short8* __restrict__ wbuf,
                             const float* __restrict__ bias,
                             float* __restrict__ out) {
    __shared__ unsigned short xl[FB_XLSZ];
    __shared__ int rowg[FB_LROWS];
    __shared__ unsigned short tabr[108];

    const int tid = threadIdx.x;
    int b = blockIdx.x;
    const int ht  = b % 14;  b /= 14;
    const int ddp = b % 8;
    const int n   = b / 8;
    const int ho0 = ht * 4;
    const int dd0 = ddp * 2;

    if (tid < FB_LROWS) {
        const int c   = tid / (6 * FB_LR);
        const int rem = tid - c * (6 * FB_LR);
        const int p   = rem / FB_LR;
        const int rl  = rem - p * FB_LR;
        const int din = dd0 - 2 + p;
        const int hin = 2 * ho0 - 3 + rl;
        const bool ok = ((unsigned)din < (unsigned)DI) && ((unsigned)hin < (unsigned)HI);
        rowg[tid] = ok ? ((n * CI + c) * DI + din) * HW_IN + hin * WI : -1;
    }
    if (tid < 108) {
        const int rc = (tid < NROW) ? tid : (NROW - 1);
        const int c  = rc / 35;
        const int kd = (rc / 7) % 5;
        const int kh = rc % 7;
        tabr[tid] = (unsigned short)(((c * 6 + kd) * FB_LR + kh) * FB_LWS);
    }
    __syncthreads();

    const int lane = tid & 63;
    const int wid  = tid >> 6;

    for (int row = wid; row < FB_LROWS; row += 8) {
        const int base = rowg[row];
        unsigned short* dst = &xl[row * FB_LWS];
        if (lane < 57) {
            float v0 = 0.0f, v1 = 0.0f;
            const int w0 = 2 * lane - 1;
            if (base >= 0) {
                if (lane >= 1)  v0 = x[base + w0];
                if (lane <= 55) v1 = x[base + w0 + 1];
            }
            *reinterpret_cast<unsigned*>(&dst[2 * lane + 2]) = pk_bf16(v0, v1);
        } else {
            const int dw = (lane == 57) ? 0 : lane;
            *reinterpret_cast<unsigned*>(&dst[2 * dw]) = 0u;
        }
    }
    __syncthreads();

    const int ddl  = wid & 1;
    const int hoL  = wid >> 1;
    const int l15  = lane & 15;
    const int kgrp = lane >> 4;
    const int woff = ddl * (FB_LR * FB_LWS) + hoL * (2 * FB_LWS);

    f32x4 acc[4][4];
    #pragma unroll
    for (int a = 0; a < 4; ++a) {
        f32x4 bv;
        #pragma unroll
        for (int r = 0; r < 4; ++r) bv[r] = bias[a * 16 + kgrp * 4 + r];
        #pragma unroll
        for (int f = 0; f < 4; ++f) acc[a][f] = bv;
    }

    const short8* wbp = wbuf + lane;
    short8 Acur[4], Anxt[4];
    #pragma unroll
    for (int a = 0; a < 4; ++a) Acur[a] = wbp[a * 64];
    int tb = (int)tabr[kgrp] + woff;

    const unsigned* xlu = reinterpret_cast<const unsigned*>(xl);

    for (int ch = 0; ch < NCH; ++ch) {
        int tbn = 0;
        if (ch + 1 < NCH) {
            tbn = (int)tabr[(ch + 1) * 4 + kgrp] + woff;
            #pragma unroll
            for (int a = 0; a < 4; ++a) Anxt[a] = wbp[((ch + 1) * 4 + a) * 64];
        }
        const unsigned* xp = xlu + (tb >> 1) + l15;
        union { unsigned u[4]; short8 s; } bx[4];
        #pragma unroll
        for (int f = 0; f < 4; ++f) {
            const unsigned* p = xp + f * 16;
            bx[f].u[0] = p[0]; bx[f].u[1] = p[1];
            bx[f].u[2] = p[2]; bx[f].u[3] = p[3];
        }
        #pragma unroll
        for (int f = 0; f < 4; ++f) {
            acc[0][f] = MFMA(Acur[0], bx[f].s, acc[0][f]);
            acc[1][f] = MFMA(Acur[1], bx[f].s, acc[1][f]);
            acc[2][f] = MFMA(Acur[2], bx[f].s, acc[2][f]);
            acc[3][f] = MFMA(Acur[3], bx[f].s, acc[3][f]);
        }
        tb = tbn;
        #pragma unroll
        for (int a = 0; a < 4; ++a) Acur[a] = Anxt[a];
    }

    const int dd = dd0 + ddl;
    const int ho = ho0 + hoL;
    #pragma unroll
    for (int f = 0; f < 4; ++f) {
        const int wo = f * 16 + l15;
        if (f < 3 || l15 < 8) {
            float* op = out + (((size_t)(n * CO) * DO_ + dd) * HO + ho) * WO + wo;
            #pragma unroll
            for (int a = 0; a < 4; ++a) {
                const int co = a * 16 + kgrp * 4;
                #pragma unroll
                for (int r = 0; r < 4; ++r)
                    op[(size_t)(co + r) * DHWO] = acc[a][f][r];
            }
        }
    }
}

extern "C" void kernel_launch(void* const* d_in, const int* in_sizes, int n_in,
                              void* d_out, int out_size, void* d_ws, size_t ws_size,
                              hipStream_t stream) {
    const float* x    = (const float*)d_in[0];
    const float* wgt  = (const float*)d_in[1];
    const float* bias = (const float*)d_in[2];
    float* out        = (float*)d_out;

    if (ws_size >= (size_t)WS_NEED) {
        unsigned* xpad = (unsigned*)d_ws;
        short8* wbuf   = (short8*)((char*)d_ws + WBUF_OFF);
        hipLaunchKernelGGL(prep_all, dim3(XP_BLOCKS + 27, 1, 1), dim3(256, 1, 1), 0,
                           stream, x, wgt, xpad, wbuf);
        hipLaunchKernelGGL(conv3d_v7, dim3(1792, 1, 1), dim3(512, 1, 1), 0, stream,
                           (const unsigned short*)xpad, wbuf, bias, out);
    } else {
        short8* wbuf = (short8*)d_ws;
        hipLaunchKernelGGL(prep_weights_fb, dim3(NCH * 4, 1, 1), dim3(64, 1, 1), 0,
                           stream, wgt, wbuf);
        hipLaunchKernelGGL(conv3d_mfma4, dim3(896, 1, 1), dim3(512, 1, 1), 0, stream,
                           x, wbuf, bias, out);
    }
}

// Round 8
// 75.457 us; speedup vs baseline: 1.3117x; 1.3117x over previous
//
#include <hip/hip_runtime.h>

// Conv3D implicit GEMM, round 8: fully-unrolled K-loop (compile-time LDS
// bases, no tab table), depth-2 pipelined A(global)+B(LDS), merge-friendly
// ds_read pairs, 64B-aligned stores, bijective XCD swizzle (1 n per XCD).
// x (8,3,16,112,112) f32, w (64,3,5,7,7), bias (64,) -> out (8,64,16,56,56) f32

typedef __attribute__((ext_vector_type(8))) short short8;
typedef __attribute__((ext_vector_type(4))) float f32x4;

#define CI 3
#define DI 16
#define HI 112
#define WI 112
#define CO 64
#define DO_ 16
#define HO 56
#define WO 56
#define HW_IN 12544
#define DHWO 50176

#define NROW 105
#define NCH 27

// xpad: bf16 [8][3][20 dpad][119 hpad][144 slots]; slot s = win s-3
#define XP_ROW 144
#define XP_H   119
#define XP_D   20
#define XPAD_BYTES  (8*3*XP_D*XP_H*XP_ROW*2)   // 16,434,432
#define WBUF_OFF    XPAD_BYTES
#define WS_NEED     (WBUF_OFF + NCH*4*64*16 + 4096)

#define SEG_SH 1296         // 9 rows * 144 shorts = 2592 B per (c,p) segment
#define SEG_DW 648

__device__ __forceinline__ unsigned short f2bf(float f) {
    unsigned u = __float_as_uint(f);
    return (unsigned short)((u + 0x7FFFu + ((u >> 16) & 1u)) >> 16);
}
__device__ __forceinline__ unsigned pk_bf16(float a, float b) {
    unsigned r;
    asm("v_cvt_pk_bf16_f32 %0, %1, %2" : "=v"(r) : "v"(a), "v"(b));
    return r;
}

// row r -> LDS dword base (clamped pad rows stay in-bounds, finite data)
__device__ __forceinline__ constexpr int rb(int r) {
    const int rc = (r < NROW) ? r : (NROW - 1);
    const int c  = rc / 35;
    const int kd = (rc / 7) % 5;
    const int kh = rc % 7;
    return (c * 6 + kd) * SEG_DW + kh * (XP_ROW / 2);
}

// ---------- fused prep: xpad (blocks 0..4016) + weights (4017..4043) ----------
#define XP_THREADS (8*3*XP_D*XP_H*18)
#define XP_BLOCKS  4017

__global__ void prep_all(const float* __restrict__ x, const float* __restrict__ wgt,
                         unsigned* __restrict__ xp, short8* __restrict__ wbuf) {
    if (blockIdx.x < XP_BLOCKS) {
        const int g = blockIdx.x * 256 + threadIdx.x;
        if (g >= XP_THREADS) return;
        const int s8 = g % 18;
        int r = g / 18;
        const int hp = r % XP_H; r /= XP_H;
        const int dp = r % XP_D; r /= XP_D;
        const int c  = r % 3;
        const int n  = r / 3;
        const int din = dp - 2, hin = hp - 3;
        const bool rowok = ((unsigned)din < (unsigned)DI) && ((unsigned)hin < (unsigned)HI);
        float v[8];
        const int w0 = 8 * s8 - 3;
        if (rowok && s8 >= 1 && s8 <= 13) {
            const float* xr = x + ((n * CI + c) * DI + din) * HW_IN + hin * WI + w0;
            #pragma unroll
            for (int j = 0; j < 8; ++j) v[j] = xr[j];
        } else if (rowok && (s8 == 0 || s8 == 14)) {
            const float* xr = x + ((n * CI + c) * DI + din) * HW_IN + hin * WI;
            #pragma unroll
            for (int j = 0; j < 8; ++j) {
                const int w = w0 + j;
                v[j] = ((unsigned)w < (unsigned)WI) ? xr[w] : 0.0f;
            }
        } else {
            #pragma unroll
            for (int j = 0; j < 8; ++j) v[j] = 0.0f;
        }
        uint4 o;
        o.x = pk_bf16(v[0], v[1]); o.y = pk_bf16(v[2], v[3]);
        o.z = pk_bf16(v[4], v[5]); o.w = pk_bf16(v[6], v[7]);
        *reinterpret_cast<uint4*>(xp + 4 * (size_t)g) = o;
    } else {
        const int t = (blockIdx.x - XP_BLOCKS) * 256 + threadIdx.x;  // 0..6911
        const int lane = t & 63;
        const int cf   = t >> 6;           // ch*4 + a
        const int l15  = lane & 15;
        const int kgrp = lane >> 4;
        const int co   = (cf & 3) * 16 + l15;
        const int rr   = (cf >> 2) * 4 + kgrp;
        const int rc   = (rr < NROW) ? rr : (NROW - 1);
        const int c    = rc / 35;
        const int kd   = (rc / 7) % 5;
        const int kh   = rc % 7;
        const float* wsrc = wgt + (((co * CI + c) * 5 + kd) * 7 + kh) * 7;
        short8 v;
        #pragma unroll
        for (int j = 0; j < 8; ++j) {
            float w = (rr < NROW && j < 7) ? wsrc[j] : 0.0f;
            v[j] = (short)f2bf(w);
        }
        wbuf[(size_t)cf * 64 + lane] = v;
    }
}

#define MFMA(A, B, C) __builtin_amdgcn_mfma_f32_16x16x32_bf16(A, B, C, 0, 0, 0)

__launch_bounds__(512, 4)
__global__ void conv3d_v8(const unsigned short* __restrict__ xpad,
                          const short8* __restrict__ wbuf,
                          const float* __restrict__ bias,
                          float* __restrict__ out) {
    __shared__ __align__(16) unsigned short xl[18 * SEG_SH];   // 46656 B

    const int tid = threadIdx.x;
    // bijective XCD swizzle: 1792 = 8 * 224; XCD k owns n = k
    int b = ((blockIdx.x & 7) * 224) + (blockIdx.x >> 3);
    const int ht  = b % 28;  b /= 28;
    const int ddp = b & 7;
    const int n   = b >> 3;
    const int ho0 = ht * 2;
    const int dd0 = ddp * 2;

    const int lane = tid & 63;
    const int wid  = tid >> 6;

    // ---- async stage: 18 (c,p) segments of 2592 B ----
    {
        const size_t nb = (size_t)(n * CI) * XP_D;
        for (int s = wid; s < 18; s += 8) {
            const int c = s / 6;
            const int p = s - c * 6;
            const char* gsrc = (const char*)(xpad +
                ((nb + (size_t)c * XP_D + (dd0 + p)) * XP_H + 2 * ho0) * XP_ROW)
                + lane * 16;
            char* ldst = (char*)&xl[s * SEG_SH];
            __builtin_amdgcn_global_load_lds(
                (const __attribute__((address_space(1))) void*)(gsrc),
                (__attribute__((address_space(3))) void*)(ldst), 16, 0, 0);
            __builtin_amdgcn_global_load_lds(
                (const __attribute__((address_space(1))) void*)(gsrc + 1024),
                (__attribute__((address_space(3))) void*)(ldst + 1024), 16, 0, 0);
            if (lane < 34)
                __builtin_amdgcn_global_load_lds(
                    (const __attribute__((address_space(1))) void*)(gsrc + 2048),
                    (__attribute__((address_space(3))) void*)(ldst + 2048), 16, 0, 0);
        }
    }
    __syncthreads();

    // ---- wave roles: ddl x hoL x woH; wave = 64co x 32wo ----
    const int ddl  = wid & 1;
    const int hoL  = (wid >> 1) & 1;
    const int woH  = wid >> 2;
    const int l15  = lane & 15;
    const int kgrp = lane >> 4;
    const int tsp  = ddl * SEG_DW + hoL * (XP_ROW / 2) * 2 + woH * 16 + l15; // dwords

    f32x4 acc[4][2];
    #pragma unroll
    for (int a = 0; a < 4; ++a) {
        f32x4 bv;
        #pragma unroll
        for (int r = 0; r < 4; ++r) bv[r] = bias[a * 16 + kgrp * 4 + r];
        acc[a][0] = bv; acc[a][1] = bv;
    }

    const short8* wbp = wbuf + lane;
    const unsigned* xlu = reinterpret_cast<const unsigned*>(xl);

    union BxU { unsigned u[8]; short8 s[2]; };
    BxU bb[3];
    short8 Ab[3][4];

    // compile-time per-chunk base, 2-level cndmask on kgrp (folds after unroll)
    auto tbase = [&](int ch) -> int {
        const int b0 = rb(ch * 4 + 0), b1 = rb(ch * 4 + 1);
        const int b2 = rb(ch * 4 + 2), b3 = rb(ch * 4 + 3);
        const int lo = (kgrp & 1) ? b1 : b0;
        const int hi = (kgrp & 1) ? b3 : b2;
        return ((kgrp & 2) ? hi : lo) + tsp;
    };
    auto loadA = [&](int ch, int slot) {
        #pragma unroll
        for (int a = 0; a < 4; ++a) Ab[slot][a] = wbp[(ch * 4 + a) * 64];
    };
    auto loadB = [&](int ch, int slot) {
        const unsigned* xp = xlu + tbase(ch);
        #pragma unroll
        for (int j = 0; j < 4; ++j) {       // (j, j+32) pairs -> ds_read2_b32
            bb[slot].u[j]     = xp[j];
            bb[slot].u[4 + j] = xp[32 + j];
        }
    };

    // prologue: chunks 0,1
    loadA(0, 0); loadB(0, 0);
    loadA(1, 1); loadB(1, 1);

    #pragma unroll
    for (int ch = 0; ch < NCH; ++ch) {      // fully unrolled: static slots/bases
        const int cur = ch % 3;
        if (ch < NCH - 2) {
            const int nx = (ch + 2) % 3;
            loadA(ch + 2, nx);
            loadB(ch + 2, nx);
        }
        #pragma unroll
        for (int a = 0; a < 4; ++a) {
            acc[a][0] = MFMA(Ab[cur][a], bb[cur].s[0], acc[a][0]);
            acc[a][1] = MFMA(Ab[cur][a], bb[cur].s[1], acc[a][1]);
        }
    }

    // ---- store: 64B-aligned wo groups {woH*16, woH*16+32} ----
    const int dd = dd0 + ddl;
    const int ho = ho0 + hoL;
    const size_t obase = ((((size_t)n * CO) * DO_ + dd) * HO + ho) * WO;
    #pragma unroll
    for (int f = 0; f < 2; ++f) {
        const int wo = woH * 16 + f * 32 + l15;
        if (wo < WO) {
            float* op = out + obase + wo;
            #pragma unroll
            for (int a = 0; a < 4; ++a) {
                const int co = a * 16 + kgrp * 4;
                #pragma unroll
                for (int r = 0; r < 4; ++r)
                    op[(size_t)(co + r) * DHWO] = acc[a][f][r];
            }
        }
    }
}

// =================== fallback (round-5 kernel) ===================
#define FB_LR 13
#define FB_LROWS 234
#define FB_LWS 144
#define FB_XLSZ (FB_LROWS*FB_LWS)

__global__ void prep_weights_fb(const float* __restrict__ wgt, short8* __restrict__ wbuf) {
    const int t    = blockIdx.x * 64 + threadIdx.x;
    const int lane = t & 63;
    const int cf   = t >> 6;
    const int l15  = lane & 15;
    const int kgrp = lane >> 4;
    const int co   = (cf & 3) * 16 + l15;
    const int rr   = (cf >> 2) * 4 + kgrp;
    const int rc   = (rr < NROW) ? rr : (NROW - 1);
    const int c    = rc / 35;
    const int kd   = (rc / 7) % 5;
    const int kh   = rc % 7;
    const float* wsrc = wgt + (((co * CI + c) * 5 + kd) * 7 + kh) * 7;
    short8 v;
    #pragma unroll
    for (int j = 0; j < 8; ++j) {
        float w = (rr < NROW && j < 7) ? wsrc[j] : 0.0f;
        v[j] = (short)f2bf(w);
    }
    wbuf[(size_t)cf * 64 + lane] = v;
}

__launch_bounds__(512, 2)
__global__ void conv3d_mfma4(const float* __restrict__ x,
                             const short8* __restrict__ wbuf,
                             const float* __restrict__ bias,
                             float* __restrict__ out) {
    __shared__ unsigned short xl[FB_XLSZ];
    __shared__ int rowg[FB_LROWS];
    __shared__ unsigned short tabr[108];

    const int tid = threadIdx.x;
    int b = blockIdx.x;
    const int ht  = b % 14;  b /= 14;
    const int ddp = b % 8;
    const int n   = b / 8;
    const int ho0 = ht * 4;
    const int dd0 = ddp * 2;

    if (tid < FB_LROWS) {
        const int c   = tid / (6 * FB_LR);
        const int rem = tid - c * (6 * FB_LR);
        const int p   = rem / FB_LR;
        const int rl  = rem - p * FB_LR;
        const int din = dd0 - 2 + p;
        const int hin = 2 * ho0 - 3 + rl;
        const bool ok = ((unsigned)din < (unsigned)DI) && ((unsigned)hin < (unsigned)HI);
        rowg[tid] = ok ? ((n * CI + c) * DI + din) * HW_IN + hin * WI : -1;
    }
    if (tid < 108) {
        const int rc = (tid < NROW) ? tid : (NROW - 1);
        const int c  = rc / 35;
        const int kd = (rc / 7) % 5;
        const int kh = rc % 7;
        tabr[tid] = (unsigned short)(((c * 6 + kd) * FB_LR + kh) * FB_LWS);
    }
    __syncthreads();

    const int lane = tid & 63;
    const int wid  = tid >> 6;

    for (int row = wid; row < FB_LROWS; row += 8) {
        const int base = rowg[row];
        unsigned short* dst = &xl[row * FB_LWS];
        if (lane < 57) {
            float v0 = 0.0f, v1 = 0.0f;
            const int w0 = 2 * lane - 1;
            if (base >= 0) {
                if (lane >= 1)  v0 = x[base + w0];
                if (lane <= 55) v1 = x[base + w0 + 1];
            }
            *reinterpret_cast<unsigned*>(&dst[2 * lane + 2]) = pk_bf16(v0, v1);
        } else {
            const int dw = (lane == 57) ? 0 : lane;
            *reinterpret_cast<unsigned*>(&dst[2 * dw]) = 0u;
        }
    }
    __syncthreads();

    const int ddl  = wid & 1;
    const int hoL  = wid >> 1;
    const int l15  = lane & 15;
    const int kgrp = lane >> 4;
    const int woff = ddl * (FB_LR * FB_LWS) + hoL * (2 * FB_LWS);

    f32x4 acc[4][4];
    #pragma unroll
    for (int a = 0; a < 4; ++a) {
        f32x4 bv;
        #pragma unroll
        for (int r = 0; r < 4; ++r) bv[r] = bias[a * 16 + kgrp * 4 + r];
        #pragma unroll
        for (int f = 0; f < 4; ++f) acc[a][f] = bv;
    }

    const short8* wbp = wbuf + lane;
    short8 Acur[4], Anxt[4];
    #pragma unroll
    for (int a = 0; a < 4; ++a) Acur[a] = wbp[a * 64];
    int tb = (int)tabr[kgrp] + woff;

    const unsigned* xlu = reinterpret_cast<const unsigned*>(xl);

    for (int ch = 0; ch < NCH; ++ch) {
        int tbn = 0;
        if (ch + 1 < NCH) {
            tbn = (int)tabr[(ch + 1) * 4 + kgrp] + woff;
            #pragma unroll
            for (int a = 0; a < 4; ++a) Anxt[a] = wbp[((ch + 1) * 4 + a) * 64];
        }
        const unsigned* xp = xlu + (tb >> 1) + l15;
        union { unsigned u[4]; short8 s; } bx[4];
        #pragma unroll
        for (int f = 0; f < 4; ++f) {
            const unsigned* p = xp + f * 16;
            bx[f].u[0] = p[0]; bx[f].u[1] = p[1];
            bx[f].u[2] = p[2]; bx[f].u[3] = p[3];
        }
        #pragma unroll
        for (int f = 0; f < 4; ++f) {
            acc[0][f] = MFMA(Acur[0], bx[f].s, acc[0][f]);
            acc[1][f] = MFMA(Acur[1], bx[f].s, acc[1][f]);
            acc[2][f] = MFMA(Acur[2], bx[f].s, acc[2][f]);
            acc[3][f] = MFMA(Acur[3], bx[f].s, acc[3][f]);
        }
        tb = tbn;
        #pragma unroll
        for (int a = 0; a < 4; ++a) Acur[a] = Anxt[a];
    }

    const int dd = dd0 + ddl;
    const int ho = ho0 + hoL;
    #pragma unroll
    for (int f = 0; f < 4; ++f) {
        const int wo = f * 16 + l15;
        if (f < 3 || l15 < 8) {
            float* op = out + (((size_t)(n * CO) * DO_ + dd) * HO + ho) * WO + wo;
            #pragma unroll
            for (int a = 0; a < 4; ++a) {
                const int co = a * 16 + kgrp * 4;
                #pragma unroll
                for (int r = 0; r < 4; ++r)
                    op[(size_t)(co + r) * DHWO] = acc[a][f][r];
            }
        }
    }
}

extern "C" void kernel_launch(void* const* d_in, const int* in_sizes, int n_in,
                              void* d_out, int out_size, void* d_ws, size_t ws_size,
                              hipStream_t stream) {
    const float* x    = (const float*)d_in[0];
    const float* wgt  = (const float*)d_in[1];
    const float* bias = (const float*)d_in[2];
    float* out        = (float*)d_out;

    if (ws_size >= (size_t)WS_NEED) {
        unsigned* xpad = (unsigned*)d_ws;
        short8* wbuf   = (short8*)((char*)d_ws + WBUF_OFF);
        hipLaunchKernelGGL(prep_all, dim3(XP_BLOCKS + 27, 1, 1), dim3(256, 1, 1), 0,
                           stream, x, wgt, xpad, wbuf);
        hipLaunchKernelGGL(conv3d_v8, dim3(1792, 1, 1), dim3(512, 1, 1), 0, stream,
                           (const unsigned short*)xpad, wbuf, bias, out);
    } else {
        short8* wbuf = (short8*)d_ws;
        hipLaunchKernelGGL(prep_weights_fb, dim3(NCH * 4, 1, 1), dim3(64, 1, 1), 0,
                           stream, wgt, wbuf);
        hipLaunchKernelGGL(conv3d_mfma4, dim3(896, 1, 1), dim3(512, 1, 1), 0, stream,
                           x, wbuf, bias, out);
    }
}

// Round 10
// 67.440 us; speedup vs baseline: 1.4676x; 1.1189x over previous
//
#include <hip/hip_runtime.h>

// Conv3D implicit GEMM, round 10: round-9 (mfma_32x32x16, a=2,f=2, forced
// depth-1 pipeline, 256-thr blocks, XCD swizzle) with the c-boundary row-base
// bug fixed: both K-half row bases computed exactly at compile time (full
// unroll) and selected per-lane by hl.
// x (8,3,16,112,112) f32, w (64,3,5,7,7), bias (64,) -> out (8,64,16,56,56) f32

typedef __attribute__((ext_vector_type(8)))  short short8;
typedef __attribute__((ext_vector_type(4)))  float f32x4;
typedef __attribute__((ext_vector_type(16))) float f32x16;

#define CI 3
#define DI 16
#define HI 112
#define WI 112
#define CO 64
#define DO_ 16
#define HO 56
#define WO 56
#define HW_IN 12544
#define DHWO 50176

#define NROW 105
#define NCH 27

// xpad: bf16 [8][3][20 dpad][119 hpad][144 slots]; slot s = win s-3
#define XP_ROW 144
#define XP_H   119
#define XP_D   20
#define XPAD_BYTES  (8*3*XP_D*XP_H*XP_ROW*2)   // 16,434,432
#define WBUF_OFF    XPAD_BYTES
#define WS_NEED     (WBUF_OFF + NCH*4*64*16 + 4096)

#define SEG_SH 1296         // 9 rows * 144 shorts (2592 B) per (c,plane) segment
#define SEG_DW 648

__device__ __forceinline__ unsigned short f2bf(float f) {
    unsigned u = __float_as_uint(f);
    return (unsigned short)((u + 0x7FFFu + ((u >> 16) & 1u)) >> 16);
}
__device__ __forceinline__ unsigned pk_bf16(float a, float b) {
    unsigned r;
    asm("v_cvt_pk_bf16_f32 %0, %1, %2" : "=v"(r) : "v"(a), "v"(b));
    return r;
}

// clamped row -> LDS dword base within (ddl=0,hoL=0): (c*6+kd)*648 + kh*72
__device__ __forceinline__ constexpr int rb2(int r) {
    const int rc = (r > 104) ? 104 : r;
    const int c  = rc / 35;
    const int kd = (rc / 7) % 5;
    const int kh = rc % 7;
    return (c * 6 + kd) * SEG_DW + kh * (XP_ROW / 2);
}

// ---------- fused prep: xpad (blocks 0..4016) + weights 32x32 layout ----------
#define XP_THREADS (8*3*XP_D*XP_H*18)
#define XP_BLOCKS  4017

__global__ void prep_all(const float* __restrict__ x, const float* __restrict__ wgt,
                         unsigned* __restrict__ xp, short8* __restrict__ wbuf) {
    if (blockIdx.x < XP_BLOCKS) {
        const int g = blockIdx.x * 256 + threadIdx.x;
        if (g >= XP_THREADS) return;
        const int s8 = g % 18;
        int r = g / 18;
        const int hp = r % XP_H; r /= XP_H;
        const int dp = r % XP_D; r /= XP_D;
        const int c  = r % 3;
        const int n  = r / 3;
        const int din = dp - 2, hin = hp - 3;
        const bool rowok = ((unsigned)din < (unsigned)DI) && ((unsigned)hin < (unsigned)HI);
        float v[8];
        const int w0 = 8 * s8 - 3;
        if (rowok && s8 >= 1 && s8 <= 13) {
            const float* xr = x + ((n * CI + c) * DI + din) * HW_IN + hin * WI + w0;
            #pragma unroll
            for (int j = 0; j < 8; ++j) v[j] = xr[j];
        } else if (rowok && (s8 == 0 || s8 == 14)) {
            const float* xr = x + ((n * CI + c) * DI + din) * HW_IN + hin * WI;
            #pragma unroll
            for (int j = 0; j < 8; ++j) {
                const int w = w0 + j;
                v[j] = ((unsigned)w < (unsigned)WI) ? xr[w] : 0.0f;
            }
        } else {
            #pragma unroll
            for (int j = 0; j < 8; ++j) v[j] = 0.0f;
        }
        uint4 o;
        o.x = pk_bf16(v[0], v[1]); o.y = pk_bf16(v[2], v[3]);
        o.z = pk_bf16(v[4], v[5]); o.w = pk_bf16(v[6], v[7]);
        *reinterpret_cast<uint4*>(xp + 4 * (size_t)g) = o;
    } else {
        // weights -> 32x32 fragment layout: frag cf = ch*4 + ks*2 + a
        // lane: co = a*32 + (lane&31), row r = ch*4 + ks*2 + (lane>>5), kw = j
        const int t = (blockIdx.x - XP_BLOCKS) * 256 + threadIdx.x;  // 0..6911
        const int lane = t & 63;
        const int cf   = t >> 6;           // 0..107
        const int q    = cf & 3;
        const int a    = q & 1;
        const int ks   = q >> 1;
        const int ch   = cf >> 2;
        const int l31  = lane & 31;
        const int hl   = lane >> 5;
        const int co   = a * 32 + l31;
        const int r    = ch * 4 + ks * 2 + hl;
        const int rc   = (r > 104) ? 104 : r;
        const int c    = rc / 35;
        const int kd   = (rc / 7) % 5;
        const int kh   = rc % 7;
        const float* wsrc = wgt + (((co * CI + c) * 5 + kd) * 7 + kh) * 7;
        short8 v;
        #pragma unroll
        for (int j = 0; j < 8; ++j) {
            float w = (r < NROW && j < 7) ? wsrc[j] : 0.0f;
            v[j] = (short)f2bf(w);
        }
        wbuf[(size_t)cf * 64 + lane] = v;
    }
}

#define MFMA32(A, B, C) __builtin_amdgcn_mfma_f32_32x32x16_bf16(A, B, C, 0, 0, 0)

__launch_bounds__(256, 3)
__global__ void conv3d_v10(const unsigned short* __restrict__ xpad,
                           const short8* __restrict__ wbuf,
                           const float* __restrict__ bias,
                           float* __restrict__ out) {
    __shared__ __align__(16) unsigned short xl[18 * SEG_SH];   // 46656 B

    const int tid = threadIdx.x;
    // bijective XCD swizzle: 1792 = 8 * 224
    int b = ((blockIdx.x & 7) * 224) + (blockIdx.x >> 3);
    const int ht  = b % 28;  b /= 28;
    const int ddp = b & 7;
    const int n   = b >> 3;
    const int ho0 = ht * 2;
    const int dd0 = ddp * 2;

    const int lane = tid & 63;
    const int wid  = tid >> 6;          // 0..3

    // ---- async stage: 18 (c,plane) segments of 2592 B ----
    {
        const size_t nb = (size_t)(n * CI) * XP_D;
        for (int s = wid; s < 18; s += 4) {
            const int c = s / 6;
            const int p = s - c * 6;
            const char* gsrc = (const char*)(xpad +
                ((nb + (size_t)c * XP_D + (dd0 + p)) * XP_H + 2 * ho0) * XP_ROW)
                + lane * 16;
            char* ldst = (char*)&xl[s * SEG_SH];
            __builtin_amdgcn_global_load_lds(
                (const __attribute__((address_space(1))) void*)(gsrc),
                (__attribute__((address_space(3))) void*)(ldst), 16, 0, 0);
            __builtin_amdgcn_global_load_lds(
                (const __attribute__((address_space(1))) void*)(gsrc + 1024),
                (__attribute__((address_space(3))) void*)(ldst + 1024), 16, 0, 0);
            if (lane < 34)
                __builtin_amdgcn_global_load_lds(
                    (const __attribute__((address_space(1))) void*)(gsrc + 2048),
                    (__attribute__((address_space(3))) void*)(ldst + 2048), 16, 0, 0);
        }
    }
    __syncthreads();

    // ---- wave roles: ddl x hoL; wave = 64co x 64wo (56 real) ----
    const int ddl = wid & 1;
    const int hoL = wid >> 1;
    const int l31 = lane & 31;
    const int hl  = lane >> 5;
    const int tspB = ddl * SEG_DW + hoL * 144 + l31;   // dwords

    f32x16 acc[2][2];
    #pragma unroll
    for (int a = 0; a < 2; ++a) {
        f32x16 bv;
        #pragma unroll
        for (int g = 0; g < 16; ++g)
            bv[g] = bias[a * 32 + (g & 3) + 8 * (g >> 2) + 4 * hl];
        acc[a][0] = bv; acc[a][1] = bv;
    }

    const short8* wbp = wbuf + lane;
    const unsigned* xlu = reinterpret_cast<const unsigned*>(xl);

    union BxU { unsigned u[4]; short8 s; };
    short8 As[2][4];     // [slot][ks*2+a]
    BxU    Bs[2][4];     // [slot][ks*2+f]

    auto loadA = [&](int ch, int slot) {
        #pragma unroll
        for (int q = 0; q < 4; ++q) As[slot][q] = wbp[(ch * 4 + q) * 64];
    };
    // FIX: exact per-row bases (compile-time after unroll), hl-select.
    auto loadB = [&](int ch, int slot) {
        #pragma unroll
        for (int ks = 0; ks < 2; ++ks) {
            const int r0 = ch * 4 + ks * 2;
            const int b0 = rb2(r0);
            const int b1 = rb2(r0 + 1);
            const int base = b0 + hl * (b1 - b0);   // hl in {0,1}
            const unsigned* xp = xlu + base + tspB;
            #pragma unroll
            for (int f = 0; f < 2; ++f) {
                const unsigned* p = xp + f * 32;
                Bs[slot][ks * 2 + f].u[0] = p[0];
                Bs[slot][ks * 2 + f].u[1] = p[1];
                Bs[slot][ks * 2 + f].u[2] = p[2];
                Bs[slot][ks * 2 + f].u[3] = p[3];
            }
        }
    };

    // prologue
    loadA(0, 0);
    loadB(0, 0);

    #pragma unroll
    for (int ch = 0; ch < NCH; ++ch) {
        if (ch + 1 < NCH) {
            loadA(ch + 1, (ch + 1) & 1);
            loadB(ch + 1, (ch + 1) & 1);
        }
        __builtin_amdgcn_sched_barrier(0);   // pin: next-chunk loads issue first
        const int s = ch & 1;
        #pragma unroll
        for (int a = 0; a < 2; ++a) {
            #pragma unroll
            for (int f = 0; f < 2; ++f) {
                acc[a][f] = MFMA32(As[s][0 + a], Bs[s][0 + f].s, acc[a][f]);
                acc[a][f] = MFMA32(As[s][2 + a], Bs[s][2 + f].s, acc[a][f]);
            }
        }
        __builtin_amdgcn_sched_barrier(0);
    }

    // ---- store: D row=(g&3)+8*(g>>2)+4*hl, col wo = f*32 + l31 ----
    const int dd = dd0 + ddl;
    const int ho = ho0 + hoL;
    const size_t obase = (size_t)n * CO * DHWO + (size_t)dd * 3136 + ho * WO;
    #pragma unroll
    for (int f = 0; f < 2; ++f) {
        const int wo = f * 32 + l31;
        if (f == 0 || l31 < 24) {
            #pragma unroll
            for (int a = 0; a < 2; ++a) {
                #pragma unroll
                for (int g = 0; g < 16; ++g) {
                    const int co = a * 32 + (g & 3) + 8 * (g >> 2) + 4 * hl;
                    out[obase + (size_t)co * DHWO + wo] = acc[a][f][g];
                }
            }
        }
    }
}

// =================== fallback (round-5 kernel, 16x16 path) ===================
#define FB_LR 13
#define FB_LROWS 234
#define FB_LWS 144
#define FB_XLSZ (FB_LROWS*FB_LWS)
#define MFMA16(A, B, C) __builtin_amdgcn_mfma_f32_16x16x32_bf16(A, B, C, 0, 0, 0)

__global__ void prep_weights_fb(const float* __restrict__ wgt, short8* __restrict__ wbuf) {
    const int t    = blockIdx.x * 64 + threadIdx.x;
    const int lane = t & 63;
    const int cf   = t >> 6;
    const int l15  = lane & 15;
    const int kgrp = lane >> 4;
    const int co   = (cf & 3) * 16 + l15;
    const int rr   = (cf >> 2) * 4 + kgrp;
    const int rc   = (rr < NROW) ? rr : (NROW - 1);
    const int c    = rc / 35;
    const int kd   = (rc / 7) % 5;
    const int kh   = rc % 7;
    const float* wsrc = wgt + (((co * CI + c) * 5 + kd) * 7 + kh) * 7;
    short8 v;
    #pragma unroll
    for (int j = 0; j < 8; ++j) {
        float w = (rr < NROW && j < 7) ? wsrc[j] : 0.0f;
        v[j] = (short)f2bf(w);
    }
    wbuf[(size_t)cf * 64 + lane] = v;
}

__launch_bounds__(512, 2)
__global__ void conv3d_mfma4(const float* __restrict__ x,
                             const short8* __restrict__ wbuf,
                             const float* __restrict__ bias,
                             float* __restrict__ out) {
    __shared__ unsigned short xl[FB_XLSZ];
    __shared__ int rowg[FB_LROWS];
    __shared__ unsigned short tabr[108];

    const int tid = threadIdx.x;
    int b = blockIdx.x;
    const int ht  = b % 14;  b /= 14;
    const int ddp = b % 8;
    const int n   = b / 8;
    const int ho0 = ht * 4;
    const int dd0 = ddp * 2;

    if (tid < FB_LROWS) {
        const int c   = tid / (6 * FB_LR);
        const int rem = tid - c * (6 * FB_LR);
        const int p   = rem / FB_LR;
        const int rl  = rem - p * FB_LR;
        const int din = dd0 - 2 + p;
        const int hin = 2 * ho0 - 3 + rl;
        const bool ok = ((unsigned)din < (unsigned)DI) && ((unsigned)hin < (unsigned)HI);
        rowg[tid] = ok ? ((n * CI + c) * DI + din) * HW_IN + hin * WI : -1;
    }
    if (tid < 108) {
        const int rc = (tid < NROW) ? tid : (NROW - 1);
        const int c  = rc / 35;
        const int kd = (rc / 7) % 5;
        const int kh = rc % 7;
        tabr[tid] = (unsigned short)(((c * 6 + kd) * FB_LR + kh) * FB_LWS);
    }
    __syncthreads();

    const int lane = tid & 63;
    const int wid  = tid >> 6;

    for (int row = wid; row < FB_LROWS; row += 8) {
        const int base = rowg[row];
        unsigned short* dst = &xl[row * FB_LWS];
        if (lane < 57) {
            float v0 = 0.0f, v1 = 0.0f;
            const int w0 = 2 * lane - 1;
            if (base >= 0) {
                if (lane >= 1)  v0 = x[base + w0];
                if (lane <= 55) v1 = x[base + w0 + 1];
            }
            *reinterpret_cast<unsigned*>(&dst[2 * lane + 2]) = pk_bf16(v0, v1);
        } else {
            const int dw = (lane == 57) ? 0 : lane;
            *reinterpret_cast<unsigned*>(&dst[2 * dw]) = 0u;
        }
    }
    __syncthreads();

    const int ddl  = wid & 1;
    const int hoL  = wid >> 1;
    const int l15  = lane & 15;
    const int kgrp = lane >> 4;
    const int woff = ddl * (FB_LR * FB_LWS) + hoL * (2 * FB_LWS);

    f32x4 acc[4][4];
    #pragma unroll
    for (int a = 0; a < 4; ++a) {
        f32x4 bv;
        #pragma unroll
        for (int r = 0; r < 4; ++r) bv[r] = bias[a * 16 + kgrp * 4 + r];
        #pragma unroll
        for (int f = 0; f < 4; ++f) acc[a][f] = bv;
    }

    const short8* wbp = wbuf + lane;
    short8 Acur[4], Anxt[4];
    #pragma unroll
    for (int a = 0; a < 4; ++a) Acur[a] = wbp[a * 64];
    int tb = (int)tabr[kgrp] + woff;

    const unsigned* xlu = reinterpret_cast<const unsigned*>(xl);

    for (int ch = 0; ch < NCH; ++ch) {
        int tbn = 0;
        if (ch + 1 < NCH) {
            tbn = (int)tabr[(ch + 1) * 4 + kgrp] + woff;
            #pragma unroll
            for (int a = 0; a < 4; ++a) Anxt[a] = wbp[((ch + 1) * 4 + a) * 64];
        }
        const unsigned* xp = xlu + (tb >> 1) + l15;
        union { unsigned u[4]; short8 s; } bx[4];
        #pragma unroll
        for (int f = 0; f < 4; ++f) {
            const unsigned* p = xp + f * 16;
            bx[f].u[0] = p[0]; bx[f].u[1] = p[1];
            bx[f].u[2] = p[2]; bx[f].u[3] = p[3];
        }
        #pragma unroll
        for (int f = 0; f < 4; ++f) {
            acc[0][f] = MFMA16(Acur[0], bx[f].s, acc[0][f]);
            acc[1][f] = MFMA16(Acur[1], bx[f].s, acc[1][f]);
            acc[2][f] = MFMA16(Acur[2], bx[f].s, acc[2][f]);
            acc[3][f] = MFMA16(Acur[3], bx[f].s, acc[3][f]);
        }
        tb = tbn;
        #pragma unroll
        for (int a = 0; a < 4; ++a) Acur[a] = Anxt[a];
    }

    const int dd = dd0 + ddl;
    const int ho = ho0 + hoL;
    #pragma unroll
    for (int f = 0; f < 4; ++f) {
        const int wo = f * 16 + l15;
        if (f < 3 || l15 < 8) {
            float* op = out + (((size_t)(n * CO) * DO_ + dd) * HO + ho) * WO + wo;
            #pragma unroll
            for (int a = 0; a < 4; ++a) {
                const int co = a * 16 + kgrp * 4;
                #pragma unroll
                for (int r = 0; r < 4; ++r)
                    op[(size_t)(co + r) * DHWO] = acc[a][f][r];
            }
        }
    }
}

extern "C" void kernel_launch(void* const* d_in, const int* in_sizes, int n_in,
                              void* d_out, int out_size, void* d_ws, size_t ws_size,
                              hipStream_t stream) {
    const float* x    = (const float*)d_in[0];
    const float* wgt  = (const float*)d_in[1];
    const float* bias = (const float*)d_in[2];
    float* out        = (float*)d_out;

    if (ws_size >= (size_t)WS_NEED) {
        unsigned* xpad = (unsigned*)d_ws;
        short8* wbuf   = (short8*)((char*)d_ws + WBUF_OFF);
        hipLaunchKernelGGL(prep_all, dim3(XP_BLOCKS + 27, 1, 1), dim3(256, 1, 1), 0,
                           stream, x, wgt, xpad, wbuf);
        // grid: 28 ho-tiles * 8 dd-pairs * 8 n = 1792 blocks of 256 threads
        hipLaunchKernelGGL(conv3d_v10, dim3(1792, 1, 1), dim3(256, 1, 1), 0, stream,
                           (const unsigned short*)xpad, wbuf, bias, out);
    } else {
        short8* wbuf = (short8*)d_ws;
        hipLaunchKernelGGL(prep_weights_fb, dim3(NCH * 4, 1, 1), dim3(64, 1, 1), 0,
                           stream, wgt, wbuf);
        hipLaunchKernelGGL(conv3d_mfma4, dim3(896, 1, 1), dim3(512, 1, 1), 0, stream,
                           x, wbuf, bias, out);
    }
}